// Round 7
// baseline (133.763 us; speedup 1.0000x reference)
//
#include <hip/hip_runtime.h>
#include <math.h>

#define PAD_IDX 0
#define BIGV 10000.0f
constexpr int B_ = 1024, S_ = 128, V_ = 200, E_ = 512, H_ = 512, T_ = 24;

// ws layout (float offsets):
//   w1Tb   [512][512] bf16 @ 0      (w1 transposed+bf16: w1Tb[k][t] = bf16(w1[t][k]))
//   h_ws   [200][512]  @ 262144
//   em_tab [200][24]   @ 364544
//   w_tab  [200][24]   @ 369344
//   emax   [200]       @ 374144
constexpr int OFF_H  = 262144;
constexpr int OFF_EM = 364544;
constexpr int OFF_W  = 369344;
constexpr int OFF_MX = 374144;

__device__ __forceinline__ unsigned short f2bf(float f) {
    unsigned u = __float_as_uint(f);
    u += 0x7fffu + ((u >> 16) & 1u);      // round-to-nearest-even
    return (unsigned short)(u >> 16);
}

// ---------------------------------------------------------------------------
// Kernel T: transpose w1 (512x512) -> bf16 via 64x64 LDS tiles (+1 pad).
// bf16 halves the h_kernel's dominant L2 stream (100 -> 50 MB). Decode in
// h_kernel is a shift (exact); only the encode here rounds (0.2% rel).
// Also zero-inits out[0] for crf's atomics.
// ---------------------------------------------------------------------------
__global__ __launch_bounds__(256) void transpose_kernel(
    const float* __restrict__ w1, unsigned short* __restrict__ w1Tb,
    float* __restrict__ out)
{
    __shared__ float tile[64][65];
    const int bi = blockIdx.x >> 3, bj = blockIdx.x & 7;
    const int tx = threadIdx.x & 63, r0 = (threadIdx.x >> 6) * 16;
    if (blockIdx.x == 0 && threadIdx.x == 0) out[0] = 0.f;
    #pragma unroll
    for (int m = 0; m < 16; ++m) {
        const int r = r0 + m;
        tile[r][tx] = w1[(size_t)(bi * 64 + r) * 512 + bj * 64 + tx];
    }
    __syncthreads();
    #pragma unroll
    for (int m = 0; m < 16; ++m) {
        const int r = r0 + m;
        w1Tb[(size_t)(bj * 64 + r) * 512 + bi * 64 + tx] = f2bf(tile[tx][r]);
    }
}

// ---------------------------------------------------------------------------
// Kernel A1: h_ws[v][t] = relu(emb[v].w1[t] + b1[t]) for a v-pair, t-half.
// Thread (part,quad): t-quad [quad*4..+3], k in [part*128..+128). Per iter:
// 1 dwordx2 load = 4 bf16 weights (decoded by shift/AND, exact), 1 LDS x-pair
// broadcast, 8 indep FMA chains. Partials combined via 8KB LDS.
// ---------------------------------------------------------------------------
__global__ __launch_bounds__(256) void h_kernel(
    const float* __restrict__ emb, const unsigned short* __restrict__ w1Tb,
    const float* __restrict__ b1, float* __restrict__ h_ws)
{
    __shared__ float xi[2 * E_];           // interleaved {x0[k], x1[k]}
    __shared__ float part_s[4][64][8];     // [k-part][t-quad][4t x 2v]
    const int pair = blockIdx.x >> 1, half = blockIdx.x & 1;
    const int v0 = pair * 2, v1 = v0 + 1;
    const int tid = threadIdx.x;

    {
        const float* __restrict__ x0 = emb + (size_t)v0 * E_;
        const float* __restrict__ x1 = emb + (size_t)v1 * E_;
        #pragma unroll
        for (int m = 0; m < 2; ++m) {
            const int k = tid + m * 256;
            xi[2 * k]     = x0[k];
            xi[2 * k + 1] = x1[k];
        }
    }
    __syncthreads();

    const int part = tid >> 6;             // 0..3  (k partition)
    const int quad = tid & 63;             // 0..63 (t quad)
    const int t0 = half * 256 + quad * 4;
    const int k0 = part * 128;

    float a0 = 0.f, a1 = 0.f, a2 = 0.f, a3 = 0.f;
    float c0 = 0.f, c1 = 0.f, c2 = 0.f, c3 = 0.f;
    const unsigned short* __restrict__ wp = w1Tb + (size_t)k0 * H_ + t0;
    const float2* __restrict__ xp = (const float2*)xi + k0;
    #pragma unroll 4
    for (int i = 0; i < 128; ++i) {
        const uint2 wu = *(const uint2*)(wp + (size_t)i * H_);
        const float2 x = xp[i];
        const float w0 = __uint_as_float(wu.x << 16);
        const float w1v = __uint_as_float(wu.x & 0xffff0000u);
        const float w2v = __uint_as_float(wu.y << 16);
        const float w3v = __uint_as_float(wu.y & 0xffff0000u);
        a0 = fmaf(w0,  x.x, a0); a1 = fmaf(w1v, x.x, a1);
        a2 = fmaf(w2v, x.x, a2); a3 = fmaf(w3v, x.x, a3);
        c0 = fmaf(w0,  x.y, c0); c1 = fmaf(w1v, x.y, c1);
        c2 = fmaf(w2v, x.y, c2); c3 = fmaf(w3v, x.y, c3);
    }
    part_s[part][quad][0] = a0; part_s[part][quad][1] = a1;
    part_s[part][quad][2] = a2; part_s[part][quad][3] = a3;
    part_s[part][quad][4] = c0; part_s[part][quad][5] = c1;
    part_s[part][quad][6] = c2; part_s[part][quad][7] = c3;
    __syncthreads();

    {
        const int q2 = tid >> 2, r0 = tid & 3;
        const float s0 = (part_s[0][q2][r0]     + part_s[1][q2][r0])
                       + (part_s[2][q2][r0]     + part_s[3][q2][r0]);
        const float s1 = (part_s[0][q2][r0 + 4] + part_s[1][q2][r0 + 4])
                       + (part_s[2][q2][r0 + 4] + part_s[3][q2][r0 + 4]);
        const int t = half * 256 + tid;
        const float bb = b1[t];
        h_ws[(size_t)v0 * H_ + t] = fmaxf(s0 + bb, 0.f);
        h_ws[(size_t)v1 * H_ + t] = fmaxf(s1 + bb, 0.f);
    }
}

// ---------------------------------------------------------------------------
// Kernel A2: em_table[v][t] = relu(h[v].w2[t] + b2[t]) (+BIG at [0][0]),
// emax[v] = row max, w_table[v][t] = exp(em - emax).
// ---------------------------------------------------------------------------
__global__ __launch_bounds__(256) void emis_kernel(
    const float* __restrict__ h_ws, const float* __restrict__ w2,
    const float* __restrict__ b2, float* __restrict__ em_table,
    float* __restrict__ w_table, float* __restrict__ emax_arr)
{
    __shared__ float em_row[32];
    const int v = blockIdx.x;
    const int t = threadIdx.x;
    const int wave = t >> 6, lane = t & 63;
    const float* __restrict__ hrow = h_ws + (size_t)v * H_;

    for (int jj2 = 0; jj2 < 6; ++jj2) {
        const int jo = wave * 6 + jj2;
        float part = 0.f;
        #pragma unroll
        for (int m = 0; m < H_ / 64; ++m) {
            const int k = lane + m * 64;
            part = fmaf(hrow[k], w2[(size_t)jo * H_ + k], part);
        }
        #pragma unroll
        for (int off = 32; off; off >>= 1)
            part += __shfl_xor(part, off, 64);
        if (lane == 0) {
            float val = fmaxf(part + b2[jo], 0.f);
            if (v == 0 && jo == PAD_IDX) val += BIGV;  // pad boost baked in
            em_row[jo] = val;
        }
    }
    __syncthreads();

    if (t < 32) {
        float x = (t < T_) ? em_row[t] : -INFINITY;
        float mx = x;
        #pragma unroll
        for (int off = 16; off; off >>= 1)
            mx = fmaxf(mx, __shfl_xor(mx, off, 32));
        if (t < T_) {
            em_table[v * T_ + t] = x;
            w_table[v * T_ + t]  = __expf(x - mx);
        }
        if (t == 0) emax_arr[v] = mx;
    }
}

// ---------------------------------------------------------------------------
// Kernel B: CRF forward, prob domain. R7: 2 independent batches per 32-lane
// group (q_A, q_B per lane) -> two interleaved recursions hide each other's
// swizzle/FMA latency. 64-thread blocks x 256 blocks = 1 wave/CU, 4 batches
// per block. Renorm every 16 steps (both chains).
// ---------------------------------------------------------------------------
#define BC(q, i) __uint_as_float(__builtin_amdgcn_ds_swizzle((q), (i) << 5))
#define ACC4D(base)                                                   \
    sA0 = fmaf(BC(qiA, (base)),     Ecol[(base)],     sA0);           \
    sB0 = fmaf(BC(qiB, (base)),     Ecol[(base)],     sB0);           \
    sA1 = fmaf(BC(qiA, (base) + 1), Ecol[(base) + 1], sA1);           \
    sB1 = fmaf(BC(qiB, (base) + 1), Ecol[(base) + 1], sB1);           \
    sA2 = fmaf(BC(qiA, (base) + 2), Ecol[(base) + 2], sA2);           \
    sB2 = fmaf(BC(qiB, (base) + 2), Ecol[(base) + 2], sB2);           \
    sA3 = fmaf(BC(qiA, (base) + 3), Ecol[(base) + 3], sA3);           \
    sB3 = fmaf(BC(qiB, (base) + 3), Ecol[(base) + 3], sB3);

__global__ __launch_bounds__(64) void crf_kernel(
    const int* __restrict__ seq, const int* __restrict__ labels,
    const float* __restrict__ start_t, const float* __restrict__ end_t,
    const float* __restrict__ trans, const float* __restrict__ em_table,
    const float* __restrict__ w_table, const float* __restrict__ emax_arr,
    float* __restrict__ out)
{
    __shared__ __align__(16) float w_s[V_ * T_];
    __shared__ float emax_s[V_];
    __shared__ int   tok_s[4 * S_];
    const int tid = threadIdx.x;
    {
        const float4* __restrict__ src = (const float4*)w_table;
        float4* dst = (float4*)w_s;
        for (int i = tid; i < V_ * T_ / 4; i += 64) dst[i] = src[i];
    }
    for (int i = tid; i < V_; i += 64) emax_s[i] = emax_arr[i];
    {
        const int base = blockIdx.x * 4 * S_;
        #pragma unroll
        for (int i = 0; i < 8; ++i)
            tok_s[tid + i * 64] = seq[base + tid + i * 64];
    }
    __syncthreads();

    const int grp = tid >> 5, j = tid & 31;
    const int bA = blockIdx.x * 4 + grp * 2;   // group handles batches bA, bA+1
    const int jj = (j < T_) ? j : 0;
    const bool act = (j < T_);
    const int* __restrict__ lrowA = labels + (size_t)bA * S_;
    const int* __restrict__ lrowB = lrowA + S_;
    const int* __restrict__ tksA  = tok_s + grp * 2 * S_;
    const int* __restrict__ tksB  = tksA + S_;

    float Ecol[T_];
    #pragma unroll
    for (int i = 0; i < T_; ++i)
        Ecol[i] = __expf(trans[i * T_ + jj]);

    // init both chains: alpha0 log-domain, one exp into prob domain
    const float st = start_t[jj];
    float qA, qB, logaccA, logaccB;
    {
        const float aA = st + em_table[tksA[0] * T_ + jj];
        const float aB = st + em_table[tksB[0] * T_ + jj];
        float mA = aA, mB = aB;
        #pragma unroll
        for (int off = 16; off; off >>= 1) {
            mA = fmaxf(mA, __shfl_xor(mA, off, 32));
            mB = fmaxf(mB, __shfl_xor(mB, off, 32));
        }
        qA = __expf(aA - mA); qB = __expf(aB - mB);
        logaccA = mA; logaccB = mB;
    }

    // software pipeline: wv = w row for step s; tok = token for step s+1
    float wvA, wvB; int tokA, tokB;
    wvA = w_s[tksA[1] * T_ + jj]; tokA = tksA[2];
    wvB = w_s[tksB[1] * T_ + jj]; tokB = tksB[2];

    for (int s = 1; s < S_; ++s) {
        const float wnA = w_s[tokA * T_ + jj];
        const float wnB = w_s[tokB * T_ + jj];
        const int nxt = (s + 2 < S_) ? s + 2 : S_ - 1;
        const int tokA2 = tksA[nxt], tokB2 = tksB[nxt];
        const unsigned qiA = __float_as_uint(qA);
        const unsigned qiB = __float_as_uint(qB);
        float sA0 = 0.f, sA1 = 0.f, sA2 = 0.f, sA3 = 0.f;
        float sB0 = 0.f, sB1 = 0.f, sB2 = 0.f, sB3 = 0.f;
        ACC4D(0) ACC4D(4) ACC4D(8) ACC4D(12) ACC4D(16) ACC4D(20)
        qA = ((sA0 + sA1) + (sA2 + sA3)) * wvA;
        qB = ((sB0 + sB1) + (sB2 + sB3)) * wvB;
        wvA = wnA; tokA = tokA2;
        wvB = wnB; tokB = tokB2;
        if ((s & 15) == 0) {                      // renorm both every 16 steps
            float mA = qA, mB = qB;
            #pragma unroll
            for (int off = 16; off; off >>= 1) {
                mA = fmaxf(mA, __shfl_xor(mA, off, 32));
                mB = fmaxf(mB, __shfl_xor(mB, off, 32));
            }
            qA *= (1.0f / mA); qB *= (1.0f / mB);
            logaccA += __logf(mA); logaccB += __logf(mB);
        }
    }

    // denominator tails
    const float ee = __expf(end_t[jj]);
    float finA = act ? qA * ee : 0.f;
    float finB = act ? qB * ee : 0.f;
    #pragma unroll
    for (int off = 16; off; off >>= 1) {
        finA += __shfl_xor(finA, off, 32);
        finB += __shfl_xor(finB, off, 32);
    }
    const float denA = logaccA + __logf(finA);   // missing Sum emax, folded below
    const float denB = logaccB + __logf(finB);

    // gold path scores minus Sum_{s>=1} emax[tok_s], both batches
    float gpA = 0.f, gpB = 0.f;
    #pragma unroll
    for (int r = 0; r < 4; ++r) {
        const int s = j + r * 32;
        {
            const int tk = tksA[s], ls = lrowA[s];
            gpA += em_table[tk * T_ + ls];
            if (s >= 1) gpA -= emax_s[tk];
            if (s < S_ - 1) gpA += trans[ls * T_ + lrowA[s + 1]];
            if (s == 0) gpA += start_t[ls];
            if (s == S_ - 1) gpA += end_t[ls];
        }
        {
            const int tk = tksB[s], ls = lrowB[s];
            gpB += em_table[tk * T_ + ls];
            if (s >= 1) gpB -= emax_s[tk];
            if (s < S_ - 1) gpB += trans[ls * T_ + lrowB[s + 1]];
            if (s == 0) gpB += start_t[ls];
            if (s == S_ - 1) gpB += end_t[ls];
        }
    }
    #pragma unroll
    for (int off = 16; off; off >>= 1) {
        gpA += __shfl_xor(gpA, off, 32);
        gpB += __shfl_xor(gpB, off, 32);
    }

    if (j == 0)
        atomicAdd(out, ((denA - gpA) + (denB - gpB)) * (1.0f / (float)B_));
}

// ---------------------------------------------------------------------------
extern "C" void kernel_launch(void* const* d_in, const int* in_sizes, int n_in,
                              void* d_out, int out_size, void* d_ws, size_t ws_size,
                              hipStream_t stream) {
    const int*   seq     = (const int*)d_in[0];
    const int*   labels  = (const int*)d_in[1];
    // d_in[2] true_lengths: unused by the reference forward
    const float* emb     = (const float*)d_in[3];
    const float* w1      = (const float*)d_in[4];
    const float* b1      = (const float*)d_in[5];
    const float* w2      = (const float*)d_in[6];
    const float* b2      = (const float*)d_in[7];
    const float* start_t = (const float*)d_in[8];
    const float* end_t   = (const float*)d_in[9];
    const float* trans   = (const float*)d_in[10];

    float* ws       = (float*)d_ws;
    unsigned short* w1Tb = (unsigned short*)d_ws;
    float* h_ws     = ws + OFF_H;
    float* em_table = ws + OFF_EM;
    float* w_table  = ws + OFF_W;
    float* emax_arr = ws + OFF_MX;
    float* out      = (float*)d_out;

    transpose_kernel<<<64, 256, 0, stream>>>(w1, w1Tb, out);
    h_kernel<<<200, 256, 0, stream>>>(emb, w1Tb, b1, h_ws);
    emis_kernel<<<V_, 256, 0, stream>>>(h_ws, w2, b2, em_table, w_table, emax_arr);
    crf_kernel<<<B_ / 4, 64, 0, stream>>>(seq, labels, start_t, end_t, trans,
                                          em_table, w_table, emax_arr, out);
}

// Round 9
// 121.190 us; speedup vs baseline: 1.1037x; 1.1037x over previous
//
#include <hip/hip_runtime.h>
#include <math.h>

#define PAD_IDX 0
#define BIGV 10000.0f
constexpr int B_ = 1024, S_ = 128, V_ = 200, E_ = 512, H_ = 512, T_ = 24;

// ws layout (float offsets):
//   w1Tb   [512][512] bf16 @ 0      (w1 transposed+bf16: w1Tb[k][t] = bf16(w1[t][k]))
//   h_ws   [200][512]  @ 262144
//   em_tab [200][24]   @ 364544
//   w_tab  [200][24]   @ 369344
//   emax   [200]       @ 374144
constexpr int OFF_H  = 262144;
constexpr int OFF_EM = 364544;
constexpr int OFF_W  = 369344;
constexpr int OFF_MX = 374144;

__device__ __forceinline__ unsigned short f2bf(float f) {
    unsigned u = __float_as_uint(f);
    u += 0x7fffu + ((u >> 16) & 1u);      // round-to-nearest-even
    return (unsigned short)(u >> 16);
}

// ---------------------------------------------------------------------------
// Kernel T: transpose w1 (512x512) -> bf16 via 64x64 LDS tiles (+1 pad).
// Also zero-inits out[0] for crf's atomics.
// ---------------------------------------------------------------------------
__global__ __launch_bounds__(256) void transpose_kernel(
    const float* __restrict__ w1, unsigned short* __restrict__ w1Tb,
    float* __restrict__ out)
{
    __shared__ float tile[64][65];
    const int bi = blockIdx.x >> 3, bj = blockIdx.x & 7;
    const int tx = threadIdx.x & 63, r0 = (threadIdx.x >> 6) * 16;
    if (blockIdx.x == 0 && threadIdx.x == 0) out[0] = 0.f;
    #pragma unroll
    for (int m = 0; m < 16; ++m) {
        const int r = r0 + m;
        tile[r][tx] = w1[(size_t)(bi * 64 + r) * 512 + bj * 64 + tx];
    }
    __syncthreads();
    #pragma unroll
    for (int m = 0; m < 16; ++m) {
        const int r = r0 + m;
        w1Tb[(size_t)(bj * 64 + r) * 512 + bi * 64 + tx] = f2bf(tile[tx][r]);
    }
}

// ---------------------------------------------------------------------------
// Kernel A1: h_ws[v][t] = relu(emb[v].w1[t] + b1[t]) (unchanged from R7).
// ---------------------------------------------------------------------------
__global__ __launch_bounds__(256) void h_kernel(
    const float* __restrict__ emb, const unsigned short* __restrict__ w1Tb,
    const float* __restrict__ b1, float* __restrict__ h_ws)
{
    __shared__ float xi[2 * E_];           // interleaved {x0[k], x1[k]}
    __shared__ float part_s[4][64][8];     // [k-part][t-quad][4t x 2v]
    const int pair = blockIdx.x >> 1, half = blockIdx.x & 1;
    const int v0 = pair * 2, v1 = v0 + 1;
    const int tid = threadIdx.x;

    {
        const float* __restrict__ x0 = emb + (size_t)v0 * E_;
        const float* __restrict__ x1 = emb + (size_t)v1 * E_;
        #pragma unroll
        for (int m = 0; m < 2; ++m) {
            const int k = tid + m * 256;
            xi[2 * k]     = x0[k];
            xi[2 * k + 1] = x1[k];
        }
    }
    __syncthreads();

    const int part = tid >> 6;
    const int quad = tid & 63;
    const int t0 = half * 256 + quad * 4;
    const int k0 = part * 128;

    float a0 = 0.f, a1 = 0.f, a2 = 0.f, a3 = 0.f;
    float c0 = 0.f, c1 = 0.f, c2 = 0.f, c3 = 0.f;
    const unsigned short* __restrict__ wp = w1Tb + (size_t)k0 * H_ + t0;
    const float2* __restrict__ xp = (const float2*)xi + k0;
    #pragma unroll 4
    for (int i = 0; i < 128; ++i) {
        const uint2 wu = *(const uint2*)(wp + (size_t)i * H_);
        const float2 x = xp[i];
        const float w0 = __uint_as_float(wu.x << 16);
        const float w1v = __uint_as_float(wu.x & 0xffff0000u);
        const float w2v = __uint_as_float(wu.y << 16);
        const float w3v = __uint_as_float(wu.y & 0xffff0000u);
        a0 = fmaf(w0,  x.x, a0); a1 = fmaf(w1v, x.x, a1);
        a2 = fmaf(w2v, x.x, a2); a3 = fmaf(w3v, x.x, a3);
        c0 = fmaf(w0,  x.y, c0); c1 = fmaf(w1v, x.y, c1);
        c2 = fmaf(w2v, x.y, c2); c3 = fmaf(w3v, x.y, c3);
    }
    part_s[part][quad][0] = a0; part_s[part][quad][1] = a1;
    part_s[part][quad][2] = a2; part_s[part][quad][3] = a3;
    part_s[part][quad][4] = c0; part_s[part][quad][5] = c1;
    part_s[part][quad][6] = c2; part_s[part][quad][7] = c3;
    __syncthreads();

    {
        const int q2 = tid >> 2, r0 = tid & 3;
        const float s0 = (part_s[0][q2][r0]     + part_s[1][q2][r0])
                       + (part_s[2][q2][r0]     + part_s[3][q2][r0]);
        const float s1 = (part_s[0][q2][r0 + 4] + part_s[1][q2][r0 + 4])
                       + (part_s[2][q2][r0 + 4] + part_s[3][q2][r0 + 4]);
        const int t = half * 256 + tid;
        const float bb = b1[t];
        h_ws[(size_t)v0 * H_ + t] = fmaxf(s0 + bb, 0.f);
        h_ws[(size_t)v1 * H_ + t] = fmaxf(s1 + bb, 0.f);
    }
}

// ---------------------------------------------------------------------------
// Kernel A2: em_table / w_table / emax (unchanged from R7).
// ---------------------------------------------------------------------------
__global__ __launch_bounds__(256) void emis_kernel(
    const float* __restrict__ h_ws, const float* __restrict__ w2,
    const float* __restrict__ b2, float* __restrict__ em_table,
    float* __restrict__ w_table, float* __restrict__ emax_arr)
{
    __shared__ float em_row[32];
    const int v = blockIdx.x;
    const int t = threadIdx.x;
    const int wave = t >> 6, lane = t & 63;
    const float* __restrict__ hrow = h_ws + (size_t)v * H_;

    for (int jj2 = 0; jj2 < 6; ++jj2) {
        const int jo = wave * 6 + jj2;
        float part = 0.f;
        #pragma unroll
        for (int m = 0; m < H_ / 64; ++m) {
            const int k = lane + m * 64;
            part = fmaf(hrow[k], w2[(size_t)jo * H_ + k], part);
        }
        #pragma unroll
        for (int off = 32; off; off >>= 1)
            part += __shfl_xor(part, off, 64);
        if (lane == 0) {
            float val = fmaxf(part + b2[jo], 0.f);
            if (v == 0 && jo == PAD_IDX) val += BIGV;  // pad boost baked in
            em_row[jo] = val;
        }
    }
    __syncthreads();

    if (t < 32) {
        float x = (t < T_) ? em_row[t] : -INFINITY;
        float mx = x;
        #pragma unroll
        for (int off = 16; off; off >>= 1)
            mx = fmaxf(mx, __shfl_xor(mx, off, 32));
        if (t < T_) {
            em_table[v * T_ + t] = x;
            w_table[v * T_ + t]  = __expf(x - mx);
        }
        if (t == 0) emax_arr[v] = mx;
    }
}

// ---------------------------------------------------------------------------
// Kernel B: CRF forward, prob domain, FWD/BWD MEET-IN-MIDDLE (R9 = R8 + fix).
// 1 wave = 1 batch. Lanes 0-31: forward chain A_s (63 steps, tokens 1..63).
// Lanes 32-63: backward chain b_k = W_{127-k} (.) (E b_{k-1}) (63 steps,
// tokens 126..64; init b_0 = W_127 (.) exp(end)). Unified step:
//   q' = (sum_i bc(q,i)*Ecoef[i]) * wv,   Ecoef = E-col (fwd) / E-row (bwd).
// R8 BUG (absmax=inf): the meet multiplied TWO chains each 15 steps past
// their last renorm (~1e21-1e22 each) -> product ~1e44 > f32 max -> inf.
// R9 FIX: renorm both halves once more after the loop, before the meet
// (u <= ~26, b <= 1, prod <= ~1250; underflow impossible since W[argmax]=1).
// ---------------------------------------------------------------------------
#define BC(q, i) __uint_as_float(__builtin_amdgcn_ds_swizzle((q), (i) << 5))
#define ACC4U(base)                                      \
    s0 = fmaf(BC(qi, (base)),     Ecoef[(base)],     s0); \
    s1 = fmaf(BC(qi, (base) + 1), Ecoef[(base) + 1], s1); \
    s2 = fmaf(BC(qi, (base) + 2), Ecoef[(base) + 2], s2); \
    s3 = fmaf(BC(qi, (base) + 3), Ecoef[(base) + 3], s3);

__global__ __launch_bounds__(256) void crf_kernel(
    const int* __restrict__ seq, const int* __restrict__ labels,
    const float* __restrict__ start_t, const float* __restrict__ end_t,
    const float* __restrict__ trans, const float* __restrict__ em_table,
    const float* __restrict__ w_table, const float* __restrict__ emax_arr,
    float* __restrict__ out)
{
    __shared__ __align__(16) float w_s[V_ * T_];
    __shared__ float emax_s[V_];
    __shared__ int   tok_s[4 * S_];
    const int tid = threadIdx.x;
    {
        const float4* __restrict__ src = (const float4*)w_table;
        float4* dst = (float4*)w_s;
        for (int i = tid; i < V_ * T_ / 4; i += 256) dst[i] = src[i];
    }
    for (int i = tid; i < V_; i += 256) emax_s[i] = emax_arr[i];
    {
        const int base = blockIdx.x * 4 * S_;
        #pragma unroll
        for (int i = 0; i < 2; ++i)
            tok_s[tid + i * 256] = seq[base + tid + i * 256];
    }
    __syncthreads();

    const int wave = tid >> 6, lane = tid & 63;
    const int b = blockIdx.x * 4 + wave;
    const int jl = lane & 31;
    const int jj = (jl < T_) ? jl : 0;
    const bool act = (jl < T_);
    const bool isF = (lane < 32);
    const int* __restrict__ lrow = labels + (size_t)b * S_;
    const int* __restrict__ tks  = tok_s + wave * S_;

    // Ecoef: fwd lane j -> E[i][j] (column), bwd lane i -> E[i][j] (row).
    float Ecoef[T_];
    #pragma unroll
    for (int i = 0; i < T_; ++i) {
        const int tix = isF ? (i * T_ + jj) : (jj * T_ + i);
        Ecoef[i] = act ? __expf(trans[tix]) : 0.f;
    }

    // init both chains (unified, per-lane selects)
    const int tokI = isF ? tks[0] : tks[S_ - 1];
    const float bse = isF ? start_t[jj] : end_t[jj];
    const float a0v = bse + em_table[tokI * T_ + jj];
    float m0 = act ? a0v : -INFINITY;
    #pragma unroll
    for (int off = 16; off; off >>= 1)
        m0 = fmaxf(m0, __shfl_xor(m0, off, 32));
    const float qFi = __expf(a0v - m0);                    // fwd init
    const float qBi = w_s[tokI * T_ + jj] * __expf(bse);   // bwd init (b_0)
    float q = act ? (isF ? qFi : qBi) : 0.f;
    float logacc = isF ? m0 : 0.f;

    // per-lane token index direction: idx(i) = off_l + dir_l * i
    const int dir_l = isF ? 1 : -1;
    const int off_l = isF ? 0 : 127;

    // software pipeline: wv = W for step 1; tokN = token for step 2
    float wv = w_s[tks[off_l + dir_l] * T_ + jj];
    int tokN = tks[off_l + dir_l * 2];

    for (int s = 1; s <= 63; ++s) {
        const float wn = w_s[tokN * T_ + jj];          // W for step s+1
        const int nxt = (s + 2 <= 63) ? s + 2 : 63;
        const int tokC = tks[off_l + dir_l * nxt];
        const unsigned qi = __float_as_uint(q);
        float s0 = 0.f, s1 = 0.f, s2 = 0.f, s3 = 0.f;
        ACC4U(0) ACC4U(4) ACC4U(8) ACC4U(12) ACC4U(16) ACC4U(20)
        q = ((s0 + s1) + (s2 + s3)) * wv;
        wv = wn; tokN = tokC;
        if ((s & 15) == 0) {                           // renorm every 16 steps
            float m = q;
            #pragma unroll
            for (int off = 16; off; off >>= 1)
                m = fmaxf(m, __shfl_xor(m, off, 32));
            q *= (1.0f / m);
            logacc += __logf(m);
        }
    }
    // fwd lanes hold A_63; bwd lanes hold b_63 (= W_64 (.) P_64).

    // R9 FIX: final renorm of BOTH halves before the meet — prevents
    // overflow of the cross-half product of two un-renormalized chains.
    {
        float m = q;
        #pragma unroll
        for (int off = 16; off; off >>= 1)
            m = fmaxf(m, __shfl_xor(m, off, 32));
        q *= (1.0f / m);
        logacc += __logf(m);
    }

    // half-step (no W): u = sum_i bc(q,i)*Ecoef[i]  (useful on fwd lanes)
    float u;
    {
        const unsigned qi = __float_as_uint(q);
        float s0 = 0.f, s1 = 0.f, s2 = 0.f, s3 = 0.f;
        ACC4U(0) ACC4U(4) ACC4U(8) ACC4U(12) ACC4U(16) ACC4U(20)
        u = (s0 + s1) + (s2 + s3);
    }

    // cross-half dot: sel = u (fwd) / b_63 (bwd); each product counted twice.
    const float sel = isF ? u : q;
    const float oth = __shfl_xor(sel, 32, 64);
    float prod = sel * oth;
    #pragma unroll
    for (int off = 32; off; off >>= 1)
        prod += __shfl_xor(prod, off, 64);
    const float logacc_o = __shfl_xor(logacc, 32, 64);
    const float denom = logacc + logacc_o + __logf(0.5f * prod);

    // gold path: lane handles steps lane and lane+64 (minus Sum_{s>=1} emax)
    float gp = 0.f;
    #pragma unroll
    for (int r = 0; r < 2; ++r) {
        const int s = lane + r * 64;
        const int tk = tks[s];
        const int ls = lrow[s];
        gp += em_table[tk * T_ + ls];
        if (s >= 1) gp -= emax_s[tk];
        if (s < S_ - 1) gp += trans[ls * T_ + lrow[s + 1]];
        if (s == 0) gp += start_t[ls];
        if (s == S_ - 1) gp += end_t[ls];
    }
    #pragma unroll
    for (int off = 32; off; off >>= 1)
        gp += __shfl_xor(gp, off, 64);

    if (lane == 0)
        atomicAdd(out, (denom - gp) * (1.0f / (float)B_));
}

// ---------------------------------------------------------------------------
extern "C" void kernel_launch(void* const* d_in, const int* in_sizes, int n_in,
                              void* d_out, int out_size, void* d_ws, size_t ws_size,
                              hipStream_t stream) {
    const int*   seq     = (const int*)d_in[0];
    const int*   labels  = (const int*)d_in[1];
    // d_in[2] true_lengths: unused by the reference forward
    const float* emb     = (const float*)d_in[3];
    const float* w1      = (const float*)d_in[4];
    const float* b1      = (const float*)d_in[5];
    const float* w2      = (const float*)d_in[6];
    const float* b2      = (const float*)d_in[7];
    const float* start_t = (const float*)d_in[8];
    const float* end_t   = (const float*)d_in[9];
    const float* trans   = (const float*)d_in[10];

    float* ws       = (float*)d_ws;
    unsigned short* w1Tb = (unsigned short*)d_ws;
    float* h_ws     = ws + OFF_H;
    float* em_table = ws + OFF_EM;
    float* w_table  = ws + OFF_W;
    float* emax_arr = ws + OFF_MX;
    float* out      = (float*)d_out;

    transpose_kernel<<<64, 256, 0, stream>>>(w1, w1Tb, out);
    h_kernel<<<200, 256, 0, stream>>>(emb, w1Tb, b1, h_ws);
    emis_kernel<<<V_, 256, 0, stream>>>(h_ws, w2, b2, em_table, w_table, emax_arr);
    crf_kernel<<<B_ / 4, 256, 0, stream>>>(seq, labels, start_t, end_t, trans,
                                           em_table, w_table, emax_arr, out);
}